// Round 8
// baseline (210.012 us; speedup 1.0000x reference)
//
#include <hip/hip_runtime.h>
#include <math.h>

#define NB 16
#define NL 1024
#define NH 8
#define NE 64
#define NWIN 1024
#define NG 64

#define SHALF 512   // s per block
#define SROW 520    // sb row stride in shorts (16B-aligned: 520*2=1040)

typedef __attribute__((ext_vector_type(8))) short short8;
typedef __attribute__((ext_vector_type(4))) float floatx4;

__device__ __forceinline__ short f2bf(float x) {
    unsigned u = __float_as_uint(x);
    u += 0x7fffu + ((u >> 16) & 1u);   // round-to-nearest-even
    return (short)(u >> 16);
}
__device__ __forceinline__ float dot4(float4 a, float4 b) {
    return fmaf(a.x, b.x, fmaf(a.y, b.y, fmaf(a.z, b.z, a.w * b.w)));
}
// Orders LDS traffic without draining vmcnt (keeps prefetch in flight).
__device__ __forceinline__ void lgkm_barrier() {
    asm volatile("s_waitcnt lgkmcnt(0)" ::: "memory");
    __builtin_amdgcn_s_barrier();
}
__device__ __forceinline__ void lgkm_wait() {
    asm volatile("s_waitcnt lgkmcnt(0)" ::: "memory");
}

#define RED16(v) { v.x += __shfl_xor(v.x, off, 64); v.y += __shfl_xor(v.y, off, 64); \
                   v.z += __shfl_xor(v.z, off, 64); v.w += __shfl_xor(v.w, off, 64); }
#define TWRITE(pa, pb, row) { \
    float4 t03, t47; \
    t03.x = tanhf(pa.x + b03.x); t03.y = tanhf(pa.y + b03.y); \
    t03.z = tanhf(pa.z + b03.z); t03.w = tanhf(pa.w + b03.w); \
    t47.x = tanhf(pb.x + b47.x); t47.y = tanhf(pb.y + b47.y); \
    t47.z = tanhf(pb.z + b47.z); t47.w = tanhf(pb.w + b47.w); \
    *(float4*)&t_lds[(row) * 8]     = t03; \
    *(float4*)&t_lds[(row) * 8 + 4] = t47; }

// Single-dispatch fused kernel. Grid 256 = (bh, s-half), 1024 threads,
// 1 block/CU (70 KB LDS), 16 waves. qp/qn duplicated x2 (per s-half) and
// reduced entirely in LDS -> no inter-block dependency, no workspace.
// Waves 0-7: MLP (4 rows / 16-lane group, 32 groups = 128 rows).
// Waves 8-15 issue k prefetch during the MLP. Then all 16 waves: qp/qn,
// attention phases A/B (wave-local), one cross-wave barrier, MFMA, atomics.
__global__ __launch_bounds__(1024, 4) void k_mega(
    const float* __restrict__ x, const float* __restrict__ mlp_w,
    const float* __restrict__ mlp_b, const float* __restrict__ q,
    const float* __restrict__ keys, const float* __restrict__ values,
    const float* __restrict__ sel_W, float* __restrict__ out)
{
    // [0,32768) w_lds (dead after MLP) | t_lds | redp | redn — all aliased
    // later by sb[64][520] (66560 B). Non-aliased tail: ap/an/wpn/qp/qn.
    __shared__ __align__(16) char smem[71680];
    float4 (*w_lds)[256] = (float4(*)[256])smem;                 // 32768
    float*  t_lds        = (float*)(smem + 32768);               // 1024 f
    float  (*redp)[64]   = (float(*)[64])(smem + 36864);         // [16][64]
    float  (*redn)[64]   = (float(*)[64])(smem + 40960);         // [16][64]
    short  (*sb)[SROW]   = (short(*)[SROW])smem;                 // 66560 B
    float*  ap_l         = (float*)(smem + 66560);               // 512 f
    float*  an_l         = (float*)(smem + 68608);               // 512 f
    float2* wpn          = (float2*)(smem + 70656);              // 64 f2
    float*  qp_l         = (float*)(smem + 71168);               // 64 f
    float*  qn_l         = (float*)(smem + 71424);               // 64 f

    int tid = threadIdx.x, blk = blockIdx.x;
    int shalf = blk & 1, bh = blk >> 1;
    int b = bh >> 3, h = bh & 7;
    int w = tid >> 6, lane = tid & 63;
    int sq = lane >> 4, c = lane & 15;
    const float scale = 0.125f;             // 1/sqrt(64)
    int s0 = shalf * SHALF;

    // ---- stage mlp_w (2 float4/thread) + wpn ----
    {
        const float4* w4 = (const float4*)mlp_w;
        float4* wl = (float4*)smem;
        wl[tid]        = w4[tid];
        wl[tid + 1024] = w4[tid + 1024];
    }
    if (tid < NG) {
        float W = sel_W[h * NG + tid];
        wpn[tid] = make_float2(fmaxf(W, 0.f) * scale, fminf(W, 0.f) * scale);
    }
    __syncthreads();

    // ---- MLP: waves 0-7, four rows per 16-lane group ----
    if (w < 8) {
        int gi = tid >> 4;                              // [0,32)
        int r0 = b * 1024 + h * 128 + gi * 4;
        const float4* x0 = (const float4*)(x + (size_t)r0 * NWIN);
        const float4* x1 = (const float4*)(x + (size_t)(r0 + 1) * NWIN);
        const float4* x2 = (const float4*)(x + (size_t)(r0 + 2) * NWIN);
        const float4* x3 = (const float4*)(x + (size_t)(r0 + 3) * NWIN);
        float4 p0a = make_float4(0,0,0,0), p0b = make_float4(0,0,0,0);
        float4 p1a = make_float4(0,0,0,0), p1b = make_float4(0,0,0,0);
        float4 p2a = make_float4(0,0,0,0), p2b = make_float4(0,0,0,0);
        float4 p3a = make_float4(0,0,0,0), p3b = make_float4(0,0,0,0);
        #pragma unroll
        for (int i = 0; i < 16; ++i) {
            float4 w0 = w_lds[0][i * 16 + c];
            float4 w1 = w_lds[1][i * 16 + c];
            float4 w2 = w_lds[2][i * 16 + c];
            float4 w3 = w_lds[3][i * 16 + c];
            float4 w4 = w_lds[4][i * 16 + c];
            float4 w5 = w_lds[5][i * 16 + c];
            float4 w6 = w_lds[6][i * 16 + c];
            float4 w7 = w_lds[7][i * 16 + c];
            float4 xa = x0[i * 16 + c], xb = x1[i * 16 + c];
            float4 xc = x2[i * 16 + c], xd = x3[i * 16 + c];
            p0a.x += dot4(xa, w0); p0a.y += dot4(xa, w1);
            p0a.z += dot4(xa, w2); p0a.w += dot4(xa, w3);
            p0b.x += dot4(xa, w4); p0b.y += dot4(xa, w5);
            p0b.z += dot4(xa, w6); p0b.w += dot4(xa, w7);
            p1a.x += dot4(xb, w0); p1a.y += dot4(xb, w1);
            p1a.z += dot4(xb, w2); p1a.w += dot4(xb, w3);
            p1b.x += dot4(xb, w4); p1b.y += dot4(xb, w5);
            p1b.z += dot4(xb, w6); p1b.w += dot4(xb, w7);
            p2a.x += dot4(xc, w0); p2a.y += dot4(xc, w1);
            p2a.z += dot4(xc, w2); p2a.w += dot4(xc, w3);
            p2b.x += dot4(xc, w4); p2b.y += dot4(xc, w5);
            p2b.z += dot4(xc, w6); p2b.w += dot4(xc, w7);
            p3a.x += dot4(xd, w0); p3a.y += dot4(xd, w1);
            p3a.z += dot4(xd, w2); p3a.w += dot4(xd, w3);
            p3b.x += dot4(xd, w4); p3b.y += dot4(xd, w5);
            p3b.z += dot4(xd, w6); p3b.w += dot4(xd, w7);
        }
        #pragma unroll
        for (int off = 1; off < 16; off <<= 1) {
            RED16(p0a) RED16(p0b) RED16(p1a) RED16(p1b)
            RED16(p2a) RED16(p2b) RED16(p3a) RED16(p3b)
        }
        float4 b03 = *(const float4*)mlp_b;
        float4 b47 = *(const float4*)(mlp_b + 4);
        if      (c == 0) TWRITE(p0a, p0b, gi * 4 + 0)
        else if (c == 1) TWRITE(p1a, p1b, gi * 4 + 1)
        else if (c == 2) TWRITE(p2a, p2b, gi * 4 + 2)
        else if (c == 3) TWRITE(p3a, p3b, gi * 4 + 3)
    }

    // ---- k prefetch (waves 8-15 issue during others' MLP) ----
    float4 kvv[8];
    #pragma unroll
    for (int p = 0; p < 8; ++p) {
        int sl = w * 32 + p * 4 + sq;
        kvv[p] = *(const float4*)(keys + (((size_t)(b * NL + s0 + sl)) * NH + h) * NE + c * 4);
    }
    __builtin_amdgcn_sched_barrier(0);

    lgkm_barrier();   // t_lds complete; k stays in flight

    // ---- qp/qn: all 16 waves, l = w*64 + i*4 + sq ----
    {
        int lo = sq, e4 = c;
        float4 accp = make_float4(0,0,0,0), accn = make_float4(0,0,0,0);
        #pragma unroll
        for (int i = 0; i < 16; ++i) {
            int l = w * 64 + i * 4 + lo;
            float tv = t_lds[l];
            float4 qv = *(const float4*)(q + (((size_t)(b * NL + l)) * NH + h) * NE + e4 * 4);
            float tp = fmaxf(tv, 0.f), tn = fminf(tv, 0.f);
            accp.x = fmaf(tp, qv.x, accp.x); accp.y = fmaf(tp, qv.y, accp.y);
            accp.z = fmaf(tp, qv.z, accp.z); accp.w = fmaf(tp, qv.w, accp.w);
            accn.x = fmaf(tn, qv.x, accn.x); accn.y = fmaf(tn, qv.y, accn.y);
            accn.z = fmaf(tn, qv.z, accn.z); accn.w = fmaf(tn, qv.w, accn.w);
        }
        #pragma unroll
        for (int off = 16; off <= 32; off <<= 1) {
            accp.x += __shfl_xor(accp.x, off, 64); accp.y += __shfl_xor(accp.y, off, 64);
            accp.z += __shfl_xor(accp.z, off, 64); accp.w += __shfl_xor(accp.w, off, 64);
            accn.x += __shfl_xor(accn.x, off, 64); accn.y += __shfl_xor(accn.y, off, 64);
            accn.z += __shfl_xor(accn.z, off, 64); accn.w += __shfl_xor(accn.w, off, 64);
        }
        if (lo == 0) {
            *(float4*)&redp[w][e4 * 4] = accp;
            *(float4*)&redn[w][e4 * 4] = accn;
        }
    }

    // ---- v prefetch: in flight until phase C ----
    int et = w & 3, q_ = w >> 2;
    const float* vbase = values + (((size_t)(b * NL + s0 + q_ * 128)) * NH + h) * NE + 16 * et + c;
    float vregA[16], vregB[16];
    #pragma unroll
    for (int m = 0; m < 16; ++m)
        vregA[m] = vbase[(size_t)((m >> 3) * 32 + sq * 8 + (m & 7)) * (NH * NE)];
    #pragma unroll
    for (int m = 0; m < 16; ++m)
        vregB[m] = vbase[(size_t)((2 + (m >> 3)) * 32 + sq * 8 + (m & 7)) * (NH * NE)];
    __builtin_amdgcn_sched_barrier(0);

    lgkm_barrier();   // redp/redn visible
    if (tid < 64) {
        float s = 0.f;
        #pragma unroll
        for (int i = 0; i < 16; ++i) s += redp[i][tid];
        qp_l[tid] = s;
    } else if (tid < 128) {
        int e = tid - 64;
        float s = 0.f;
        #pragma unroll
        for (int i = 0; i < 16; ++i) s += redn[i][e];
        qn_l[e] = s;
    }
    lgkm_barrier();   // qp_l/qn_l ready

    const float4 qp4 = *(const float4*)&qp_l[c * 4];
    const float4 qn4 = *(const float4*)&qn_l[c * 4];

    // ---- phase A: ap/an, wave owns 32 s of the 512 ----
    #pragma unroll
    for (int p = 0; p < 8; ++p) {
        int sl = w * 32 + p * 4 + sq;
        float pp = dot4(kvv[p], qp4);
        float pn = dot4(kvv[p], qn4);
        #pragma unroll
        for (int m_ = 1; m_ <= 8; m_ <<= 1) {
            pp += __shfl_xor(pp, m_, 64);
            pn += __shfl_xor(pn, m_, 64);
        }
        if (c == 0) { ap_l[sl] = pp; an_l[sl] = pn; }
    }
    lgkm_wait();   // wave-local RAW

    // ---- phase B: softmax, lane owns (s = w*32+(lane&31), g-half) ----
    {
        int s_ = w * 32 + (lane & 31);
        int g0 = (lane >> 5) * 32;
        float ap = ap_l[s_], an = an_l[s_];
        const float2* wv_ = &wpn[g0];
        float m = -1e30f;
        #pragma unroll 8
        for (int g = 0; g < 32; ++g) {
            float2 wv = wv_[g];
            m = fmaxf(m, fmaf(wv.x, ap, wv.y * an));
        }
        m = fmaxf(m, __shfl_xor(m, 32, 64));
        float d = 0.f;
        #pragma unroll 8
        for (int g = 0; g < 32; ++g) {
            float2 wv = wv_[g];
            d += __expf(fmaf(wv.x, ap, wv.y * an) - m);
        }
        d += __shfl_xor(d, 32, 64);
        float inv = 1.0f / d;
        #pragma unroll 8
        for (int g = 0; g < 32; ++g) {
            float2 wv = wv_[g];
            sb[g0 + g][s_] = f2bf(__expf(fmaf(wv.x, ap, wv.y * an) - m) * inv);
        }
    }
    lgkm_barrier();   // sb complete (cross-wave)

    // ---- phase C: MFMA, wave = (e-tile et, s-quarter q_) ----
    floatx4 acc[4] = {{0.f,0.f,0.f,0.f},{0.f,0.f,0.f,0.f},
                      {0.f,0.f,0.f,0.f},{0.f,0.f,0.f,0.f}};
    #pragma unroll
    for (int ks = 0; ks < 4; ++ks) {
        short8 av;
        #pragma unroll
        for (int j = 0; j < 8; ++j)
            av[j] = f2bf(ks < 2 ? vregA[ks * 8 + j] : vregB[(ks - 2) * 8 + j]);
        #pragma unroll
        for (int n = 0; n < 4; ++n) {
            short8 bv = *(const short8*)&sb[16 * n + c][q_ * 128 + ks * 32 + sq * 8];
            acc[n] = __builtin_amdgcn_mfma_f32_16x16x32_bf16(av, bv, acc[n], 0, 0, 0);
        }
    }

    // epilogue: 4 s-quarters x 2 s-halves accumulate per (b,h) -> atomics
    #pragma unroll
    for (int n = 0; n < 4; ++n) {
        #pragma unroll
        for (int r = 0; r < 4; ++r) {
            int e = 16 * et + sq * 4 + r;
            int g = 16 * n + c;
            atomicAdd(&out[((size_t)(b * NE + e) * NH + h) * NG + g], acc[n][r]);
        }
    }
}

extern "C" void kernel_launch(void* const* d_in, const int* in_sizes, int n_in,
                              void* d_out, int out_size, void* d_ws, size_t ws_size,
                              hipStream_t stream) {
    (void)in_sizes; (void)n_in; (void)d_ws; (void)ws_size;
    const float* queries = (const float*)d_in[0];
    const float* keys    = (const float*)d_in[1];
    const float* values  = (const float*)d_in[2];
    const float* x       = (const float*)d_in[3];
    const float* mlp_w   = (const float*)d_in[4];
    const float* mlp_b   = (const float*)d_in[5];
    const float* sel_W   = (const float*)d_in[6];
    float* out = (float*)d_out;

    hipMemsetAsync(out, 0, (size_t)out_size * sizeof(float), stream);
    k_mega<<<dim3(NB * NH * 2), dim3(1024), 0, stream>>>(
        x, mlp_w, mlp_b, queries, keys, values, sel_W, out);
}